// Round 15
// baseline (372.611 us; speedup 1.0000x reference)
//
#include <hip/hip_runtime.h>
#include <math.h>
#include <stdint.h>

// ============================================================================
// Numerics contract (DO NOT CHANGE — rounds 6-14 passed with exactly this):
//  * every sign-critical dot product = BLAS sgemm per-element DAG:
//    acc=0; for k=0..d-1 ascending: acc = fmaf(a,b,acc)  (single acc, fused)
//  * row sums = numpy pairwise_sum avx512f replica (16 leaves of 128, 8x16-lane
//    accs, ((r0+r1)+(r2+r3))+((r4+r5)+(r6+r7)), reduce_add xor-tree 8/4/2/1,
//    perfect binary tree over leaves)
//  * thr = fl(fl(wii/rs) * tv);  x = fl(fl(w/rs) - thr);  pos iff x >= 0
//  * tz sigmoid via double-exp (feeds thr -> sign-critical)
// Tiling/fusion changes scheduling only, never per-element DAGs. __expf only
// on value-paths (p into stats, p and tau in phi), never on sign decisions.
// ============================================================================

__device__ __forceinline__ float mrn(float a, float b) { return __fmul_rn(a, b); }
__device__ __forceinline__ float arn(float a, float b) { return __fadd_rn(a, b); }

#define GBK 16

// =====================================================================
// Kernel A: static mask. 256x128 tile, 512 threads, 8x8/thread —
// graph's proven structure applied to S·S^T. mask = (sim > 0).
// =====================================================================
__global__ __launch_bounds__(512)
void mask_kernel(const float* __restrict__ S, unsigned char* __restrict__ mask,
                 int n, int d) {
  __shared__ float Xk[GBK][260];   // A: 256 rows of S
  __shared__ float Yk[GBK][132];   // B: 128 rows of S
  const int t = threadIdx.x;
  const int tx = t & 15, ty = t >> 4;            // ty 0..31, tx 0..15
  const int row0 = blockIdx.y * 256, col0 = blockIdx.x * 128;
  const int ra = t >> 1, qa = t & 1;
  const int rb = t >> 2, qb = t & 3;
  float acc[8][8] = {};
  for (int kc = 0; kc < d; kc += GBK) {
    __syncthreads();
    const float* xp = &S[(size_t)(row0 + ra) * d + kc + qa * 8];
    float4 v0 = *reinterpret_cast<const float4*>(xp);
    float4 v1 = *reinterpret_cast<const float4*>(xp + 4);
    const float* yp = &S[(size_t)(col0 + rb) * d + kc + qb * 4];
    float4 u0 = *reinterpret_cast<const float4*>(yp);
    Xk[qa*8+0][ra] = v0.x; Xk[qa*8+1][ra] = v0.y; Xk[qa*8+2][ra] = v0.z; Xk[qa*8+3][ra] = v0.w;
    Xk[qa*8+4][ra] = v1.x; Xk[qa*8+5][ra] = v1.y; Xk[qa*8+6][ra] = v1.z; Xk[qa*8+7][ra] = v1.w;
    Yk[qb*4+0][rb] = u0.x; Yk[qb*4+1][rb] = u0.y; Yk[qb*4+2][rb] = u0.z; Yk[qb*4+3][rb] = u0.w;
    __syncthreads();
#pragma unroll
    for (int k = 0; k < GBK; ++k) {
      float4 a0 = *reinterpret_cast<const float4*>(&Xk[k][ty * 8]);
      float4 a1 = *reinterpret_cast<const float4*>(&Xk[k][ty * 8 + 4]);
      float4 b0 = *reinterpret_cast<const float4*>(&Yk[k][tx * 4]);
      float4 b1 = *reinterpret_cast<const float4*>(&Yk[k][64 + tx * 4]);
      float a[8] = {a0.x, a0.y, a0.z, a0.w, a1.x, a1.y, a1.z, a1.w};
      float b[8] = {b0.x, b0.y, b0.z, b0.w, b1.x, b1.y, b1.z, b1.w};
#pragma unroll
      for (int i2 = 0; i2 < 8; ++i2)
#pragma unroll
        for (int j2 = 0; j2 < 8; ++j2)
          acc[i2][j2] = __builtin_fmaf(a[i2], b[j2], acc[i2][j2]);
    }
  }
#pragma unroll
  for (int i2 = 0; i2 < 8; ++i2) {
    int gi = row0 + ty * 8 + i2;
    unsigned lo = 0, hi = 0;
#pragma unroll
    for (int j2 = 0; j2 < 4; ++j2) {
      lo |= (acc[i2][j2]     > 0.0f ? 1u : 0u) << (8 * j2);
      hi |= (acc[i2][4 + j2] > 0.0f ? 1u : 0u) << (8 * j2);
    }
    *reinterpret_cast<unsigned*>(&mask[(size_t)gi * n + col0 + tx * 4])      = lo;
    *reinterpret_cast<unsigned*>(&mask[(size_t)gi * n + col0 + 64 + tx * 4]) = hi;
  }
}

// =====================================================================
// Kernel B: graph GEMM. 256x128 tile, 512 threads, 8x8/thread,
// XCD-aware decode (bz = lin % 8). w = relu(g*mask)+1e-10  [R14 verbatim]
// =====================================================================
__global__ __launch_bounds__(512)
void graph_kernel(const float* __restrict__ cur_, const float* __restrict__ prev,
                  const unsigned char* __restrict__ mask, float* __restrict__ wout,
                  int n, int d, int bcnt, int nbx) {
  const int lin = blockIdx.x;
  const int bz = lin % bcnt;
  const int inner = lin / bcnt;
  const int bx = inner % nbx;
  const int by = inner / nbx;
  __shared__ float Xk[GBK][260];
  __shared__ float Yk[GBK][132];
  const int t = threadIdx.x;
  const int tx = t & 15, ty = t >> 4;
  const int row0 = by * 256, col0 = bx * 128;
  const float* X = cur_ + (size_t)bz * n * d;
  const float* Y = prev + (size_t)bz * n * d;
  const int ra = t >> 1, qa = t & 1;
  const int rb = t >> 2, qb = t & 3;
  float acc[8][8] = {};
  for (int kc = 0; kc < d; kc += GBK) {
    __syncthreads();
    const float* xp = &X[(size_t)(row0 + ra) * d + kc + qa * 8];
    float4 v0 = *reinterpret_cast<const float4*>(xp);
    float4 v1 = *reinterpret_cast<const float4*>(xp + 4);
    const float* yp = &Y[(size_t)(col0 + rb) * d + kc + qb * 4];
    float4 u0 = *reinterpret_cast<const float4*>(yp);
    Xk[qa*8+0][ra] = v0.x; Xk[qa*8+1][ra] = v0.y; Xk[qa*8+2][ra] = v0.z; Xk[qa*8+3][ra] = v0.w;
    Xk[qa*8+4][ra] = v1.x; Xk[qa*8+5][ra] = v1.y; Xk[qa*8+6][ra] = v1.z; Xk[qa*8+7][ra] = v1.w;
    Yk[qb*4+0][rb] = u0.x; Yk[qb*4+1][rb] = u0.y; Yk[qb*4+2][rb] = u0.z; Yk[qb*4+3][rb] = u0.w;
    __syncthreads();
#pragma unroll
    for (int k = 0; k < GBK; ++k) {
      float4 a0 = *reinterpret_cast<const float4*>(&Xk[k][ty * 8]);
      float4 a1 = *reinterpret_cast<const float4*>(&Xk[k][ty * 8 + 4]);
      float4 b0 = *reinterpret_cast<const float4*>(&Yk[k][tx * 4]);
      float4 b1 = *reinterpret_cast<const float4*>(&Yk[k][64 + tx * 4]);
      float a[8] = {a0.x, a0.y, a0.z, a0.w, a1.x, a1.y, a1.z, a1.w};
      float b[8] = {b0.x, b0.y, b0.z, b0.w, b1.x, b1.y, b1.z, b1.w};
#pragma unroll
      for (int i2 = 0; i2 < 8; ++i2)
#pragma unroll
        for (int j2 = 0; j2 < 8; ++j2)
          acc[i2][j2] = __builtin_fmaf(a[i2], b[j2], acc[i2][j2]);
    }
  }
#pragma unroll
  for (int i2 = 0; i2 < 8; ++i2) {
    int gi = row0 + ty * 8 + i2;
    size_t rbase = (size_t)bz * n * n + (size_t)gi * n;
    unsigned mlo = *reinterpret_cast<const unsigned*>(&mask[(size_t)gi * n + col0 + tx * 4]);
    unsigned mhi = *reinterpret_cast<const unsigned*>(&mask[(size_t)gi * n + col0 + 64 + tx * 4]);
    float4 o0, o1;
    o0.x = arn(fmaxf(mrn(acc[i2][0], (float)(mlo & 0xff)), 0.0f), 1e-10f);
    o0.y = arn(fmaxf(mrn(acc[i2][1], (float)((mlo >> 8) & 0xff)), 0.0f), 1e-10f);
    o0.z = arn(fmaxf(mrn(acc[i2][2], (float)((mlo >> 16) & 0xff)), 0.0f), 1e-10f);
    o0.w = arn(fmaxf(mrn(acc[i2][3], (float)((mlo >> 24) & 0xff)), 0.0f), 1e-10f);
    o1.x = arn(fmaxf(mrn(acc[i2][4], (float)(mhi & 0xff)), 0.0f), 1e-10f);
    o1.y = arn(fmaxf(mrn(acc[i2][5], (float)((mhi >> 8) & 0xff)), 0.0f), 1e-10f);
    o1.z = arn(fmaxf(mrn(acc[i2][6], (float)((mhi >> 16) & 0xff)), 0.0f), 1e-10f);
    o1.w = arn(fmaxf(mrn(acc[i2][7], (float)((mhi >> 24) & 0xff)), 0.0f), 1e-10f);
    *reinterpret_cast<float4*>(&wout[rbase + col0 + tx * 4])      = o0;
    *reinterpret_cast<float4*>(&wout[rbase + col0 + 64 + tx * 4]) = o1;
  }
}

// =====================================================================
// Kernel C: t = sigmoid(FMA-chain dot(cur_row, pool))  [sign-critical:
// double-exp kept]
// =====================================================================
__global__ __launch_bounds__(256)
void tz_kernel(const float* __restrict__ cur, const float* __restrict__ pool,
               float* __restrict__ tv, int nrows, int d) {
  int row = blockIdx.x * 256 + threadIdx.x;
  if (row >= nrows) return;
  const float* x = cur + (size_t)row * d;
  float acc = 0.0f;
  for (int k = 0; k < d; ++k) acc = __builtin_fmaf(x[k], pool[k], acc);
  float e = (float)exp(-(double)acc);
  tv[row] = __fdiv_rn(1.0f, arn(1.0f, e));
}

// =====================================================================
// Kernel D: per-row {pairwise rowsum DAG, thr, stats partials}; row
// LDS-staged once. [R14 verbatim]
// =====================================================================
__global__ __launch_bounds__(256)
void rowstat_kernel(const float* __restrict__ wbuf, const float* __restrict__ tv,
                    float* __restrict__ rsv, float* __restrict__ thrv,
                    double* __restrict__ cpart, int n) {
  const int row = blockIdx.x;
  const int t = threadIdx.x;
  const float* a = wbuf + (size_t)row * n;
  const int i = row % n;
  __shared__ float sr[2048];
  *reinterpret_cast<float4*>(&sr[t * 4])        = *reinterpret_cast<const float4*>(&a[t * 4]);
  *reinterpret_cast<float4*>(&sr[1024 + t * 4]) = *reinterpret_cast<const float4*>(&a[1024 + t * 4]);
  __syncthreads();
  const int kleaf = t >> 4, l = t & 15;
  __shared__ float leaf[16];
  __shared__ float sh_rs, sh_thr;
  {
    const float* base = sr + kleaf * 128;
    float r0 = base[l],      r1 = base[16 + l],  r2 = base[32 + l],  r3 = base[48 + l];
    float r4 = base[64 + l], r5 = base[80 + l],  r6 = base[96 + l],  r7 = base[112 + l];
    float v = arn(arn(arn(r0, r1), arn(r2, r3)), arn(arn(r4, r5), arn(r6, r7)));
    v = arn(v, __shfl_xor(v, 8));
    v = arn(v, __shfl_xor(v, 4));
    v = arn(v, __shfl_xor(v, 2));
    v = arn(v, __shfl_xor(v, 1));
    if (l == 0) leaf[kleaf] = v;
  }
  __syncthreads();
  if (t == 0) {
    float t1[8], t2[4], t3[2];
#pragma unroll
    for (int k2 = 0; k2 < 8; ++k2) t1[k2] = arn(leaf[2*k2], leaf[2*k2+1]);
#pragma unroll
    for (int k2 = 0; k2 < 4; ++k2) t2[k2] = arn(t1[2*k2], t1[2*k2+1]);
#pragma unroll
    for (int k2 = 0; k2 < 2; ++k2) t3[k2] = arn(t2[2*k2], t2[2*k2+1]);
    float rs = arn(t3[0], t3[1]);
    float tb = __fdiv_rn(sr[i], rs);
    float th = mrn(tb, tv[row]);
    sh_rs = rs; sh_thr = th;
    rsv[row] = rs; thrv[row] = th;
  }
  __syncthreads();
  const float rs = sh_rs, thr = sh_thr;
  double s1 = 0.0, s2 = 0.0;
  for (int off = 0; off < n; off += 1024) {
    float4 wv = *reinterpret_cast<const float4*>(&sr[off + t * 4]);
    float wa[4] = {wv.x, wv.y, wv.z, wv.w};
#pragma unroll
    for (int c = 0; c < 4; ++c) {
      float probs = __fdiv_rn(wa[c], rs);
      float x = __fsub_rn(probs, thr);
      if (x >= 0.0f) {
        float pv = __fdiv_rn(1.0f, arn(1.0f, __expf(-x)));
        s1 += (double)pv;
        s2 += (double)pv * (double)pv;
      }
    }
  }
  __shared__ double sh1[256], sh2[256];
  sh1[t] = s1; sh2[t] = s2;
  __syncthreads();
  for (int s = 128; s > 0; s >>= 1) {
    if (t < s) { sh1[t] += sh1[t + s]; sh2[t] += sh2[t + s]; }
    __syncthreads();
  }
  if (t == 0) {
    cpart[(size_t)row * 2 + 0] = sh1[0];
    cpart[(size_t)row * 2 + 1] = sh2[0];
  }
}

// =====================================================================
// Kernel E: per-batch mean / inv-std (biased) from per-row partials
// =====================================================================
__global__ __launch_bounds__(256)
void stats_kernel(const double* __restrict__ cpart, float* __restrict__ bstats,
                  int nb, double inv_nn) {
  int b = blockIdx.x, t = threadIdx.x;
  double s1 = 0.0, s2 = 0.0;
  for (int c = t; c < nb; c += 256) {
    s1 += cpart[((size_t)b * nb + c) * 2 + 0];
    s2 += cpart[((size_t)b * nb + c) * 2 + 1];
  }
  __shared__ double sh1[256], sh2[256];
  sh1[t] = s1; sh2[t] = s2;
  __syncthreads();
  for (int s = 128; s > 0; s >>= 1) {
    if (t < s) { sh1[t] += sh1[t + s]; sh2[t] += sh2[t + s]; }
    __syncthreads();
  }
  if (t == 0) {
    double mean = sh1[0] * inv_nn;
    double var = sh2[0] * inv_nn - mean * mean;
    bstats[b * 2 + 0] = (float)mean;
    bstats[b * 2 + 1] = (float)(1.0 / sqrt(var + 1e-5));
  }
}

// =====================================================================
// Kernel F: phi in-place. One block per row (256 thr x 2 float4);
// rs/thr/bstats loaded once per thread. Sign chain identical.
// =====================================================================
__global__ __launch_bounds__(256)
void phi_kernel(float4* __restrict__ buf, const float* __restrict__ rsv,
                const float* __restrict__ thrv, const float* __restrict__ bstats,
                const float* __restrict__ gamma, const float* __restrict__ beta,
                int nq4, int n) {
  const int row = blockIdx.x;
  const int b = row / n;                 // scalar, once
  const float rs = rsv[row], thr = thrv[row];
  const float mean = bstats[b * 2 + 0];
  const float inv = bstats[b * 2 + 1];
  const float ga = gamma[0] * 2.0f;
  const float be = beta[0] * 2.0f;
  float4* rp = buf + (size_t)row * nq4;
  const int t = threadIdx.x;
#pragma unroll
  for (int half = 0; half < 2; ++half) {
    int e = half * 256 + t;
    float4 v = rp[e];
    float wa[4] = {v.x, v.y, v.z, v.w};
    float oa[4];
#pragma unroll
    for (int c = 0; c < 4; ++c) {
      float probs = __fdiv_rn(wa[c], rs);
      float x = __fsub_rn(probs, thr);
      float p = 0.0f, m = 1.0f;
      if (x >= 0.0f) {
        p = __fdiv_rn(1.0f, arn(1.0f, __expf(-x)));
        m = p;
      }
      float xn = (p - mean) * inv;
      oa[c] = __expf(__builtin_fmaf(ga, xn, be)) * m;
    }
    v.x = oa[0]; v.y = oa[1]; v.z = oa[2]; v.w = oa[3];
    rp[e] = v;
  }
}

extern "C" void kernel_launch(void* const* d_in, const int* in_sizes, int n_in,
                              void* d_out, int out_size, void* d_ws, size_t ws_size,
                              hipStream_t stream) {
  const float* S     = (const float*)d_in[0];
  const float* cur   = (const float*)d_in[1];
  const float* prev  = (const float*)d_in[2];
  const float* pool  = (const float*)d_in[3];
  const float* gamma = (const float*)d_in[4];
  const float* beta  = (const float*)d_in[5];
  const int d = in_sizes[3];
  const int n = in_sizes[0] / d;
  const int b = in_sizes[1] / (n * d);
  float* out = (float*)d_out;

  const int nrows = b * n;
  const int nbx = n / 128, nby = n / 256;

  char* ws = (char*)d_ws;
  float* tv   = (float*)ws; ws += (size_t)nrows * sizeof(float);
  float* rsv  = (float*)ws; ws += (size_t)nrows * sizeof(float);
  float* thrv = (float*)ws; ws += (size_t)nrows * sizeof(float);
  ws = (char*)(((uintptr_t)ws + 15) & ~(uintptr_t)15);
  double* cpart = (double*)ws; ws += (size_t)nrows * 2 * sizeof(double);
  float* bstats = (float*)ws;  ws += 64;
  unsigned char* mask = (unsigned char*)ws;   // n*n bytes

  hipLaunchKernelGGL(mask_kernel, dim3(nbx, nby), dim3(512), 0, stream,
                     S, mask, n, d);
  hipLaunchKernelGGL(tz_kernel, dim3((nrows + 255) / 256), dim3(256), 0, stream,
                     cur, pool, tv, nrows, d);
  hipLaunchKernelGGL(graph_kernel, dim3(nbx * nby * b), dim3(512), 0, stream,
                     cur, prev, mask, out, n, d, b, nbx);
  hipLaunchKernelGGL(rowstat_kernel, dim3(nrows), dim3(256), 0, stream,
                     out, tv, rsv, thrv, cpart, n);
  hipLaunchKernelGGL(stats_kernel, dim3(b), dim3(256), 0, stream,
                     cpart, bstats, n, 1.0 / ((double)n * (double)n));
  hipLaunchKernelGGL(phi_kernel, dim3(nrows), dim3(256), 0, stream,
                     (float4*)out, rsv, thrv, bstats, gamma, beta, n / 4, n);
}

// Round 16
// 356.695 us; speedup vs baseline: 1.0446x; 1.0446x over previous
//
#include <hip/hip_runtime.h>
#include <math.h>
#include <stdint.h>

// ============================================================================
// Numerics contract (DO NOT CHANGE — rounds 6-15 passed with exactly this):
//  * every sign-critical dot product = BLAS sgemm per-element DAG:
//    acc=0; for k=0..d-1 ascending: acc = fmaf(a,b,acc)  (single acc, fused)
//  * row sums = numpy pairwise_sum avx512f replica (16 leaves of 128, 8x16-lane
//    accs, ((r0+r1)+(r2+r3))+((r4+r5)+(r6+r7)), reduce_add xor-tree 8/4/2/1,
//    perfect binary tree over leaves)
//  * thr = fl(fl(wii/rs) * tv);  x = fl(fl(w/rs) - thr);  pos iff x >= 0
//  * tz sigmoid via double-exp (feeds thr -> sign-critical)
// This is the R14 configuration verbatim — best measured (357.4 us).
// ============================================================================

__device__ __forceinline__ float mrn(float a, float b) { return __fmul_rn(a, b); }
__device__ __forceinline__ float arn(float a, float b) { return __fadd_rn(a, b); }

#define GBK 16

// =====================================================================
// Kernel A: static mask. 128x128 tile, 256 thr, 8x8/thread (R9 struct).
// =====================================================================
__global__ __launch_bounds__(256)
void mask_kernel(const float* __restrict__ S, unsigned char* __restrict__ mask,
                 int n, int d) {
  __shared__ float Xk[GBK][132];
  __shared__ float Yk[GBK][132];
  const int t = threadIdx.x, tx = t & 15, ty = t >> 4;
  const int row0 = blockIdx.y * 128, col0 = blockIdx.x * 128;
  const int r = t >> 1, q = t & 1;
  float acc[8][8] = {};
  for (int kc = 0; kc < d; kc += GBK) {
    __syncthreads();
    const float* xp = &S[(size_t)(row0 + r) * d + kc + q * 8];
    float4 v0 = *reinterpret_cast<const float4*>(xp);
    float4 v1 = *reinterpret_cast<const float4*>(xp + 4);
    const float* yp = &S[(size_t)(col0 + r) * d + kc + q * 8];
    float4 u0 = *reinterpret_cast<const float4*>(yp);
    float4 u1 = *reinterpret_cast<const float4*>(yp + 4);
    Xk[q*8+0][r] = v0.x; Xk[q*8+1][r] = v0.y; Xk[q*8+2][r] = v0.z; Xk[q*8+3][r] = v0.w;
    Xk[q*8+4][r] = v1.x; Xk[q*8+5][r] = v1.y; Xk[q*8+6][r] = v1.z; Xk[q*8+7][r] = v1.w;
    Yk[q*8+0][r] = u0.x; Yk[q*8+1][r] = u0.y; Yk[q*8+2][r] = u0.z; Yk[q*8+3][r] = u0.w;
    Yk[q*8+4][r] = u1.x; Yk[q*8+5][r] = u1.y; Yk[q*8+6][r] = u1.z; Yk[q*8+7][r] = u1.w;
    __syncthreads();
#pragma unroll
    for (int k = 0; k < GBK; ++k) {
      float4 a0 = *reinterpret_cast<const float4*>(&Xk[k][ty * 8]);
      float4 a1 = *reinterpret_cast<const float4*>(&Xk[k][ty * 8 + 4]);
      float4 b0 = *reinterpret_cast<const float4*>(&Yk[k][tx * 4]);
      float4 b1 = *reinterpret_cast<const float4*>(&Yk[k][64 + tx * 4]);
      float a[8] = {a0.x, a0.y, a0.z, a0.w, a1.x, a1.y, a1.z, a1.w};
      float b[8] = {b0.x, b0.y, b0.z, b0.w, b1.x, b1.y, b1.z, b1.w};
#pragma unroll
      for (int i2 = 0; i2 < 8; ++i2)
#pragma unroll
        for (int j2 = 0; j2 < 8; ++j2)
          acc[i2][j2] = __builtin_fmaf(a[i2], b[j2], acc[i2][j2]);
    }
  }
#pragma unroll
  for (int i2 = 0; i2 < 8; ++i2) {
    int gi = row0 + ty * 8 + i2;
    unsigned lo = 0, hi = 0;
#pragma unroll
    for (int j2 = 0; j2 < 4; ++j2) {
      lo |= (acc[i2][j2]     > 0.0f ? 1u : 0u) << (8 * j2);
      hi |= (acc[i2][4 + j2] > 0.0f ? 1u : 0u) << (8 * j2);
    }
    *reinterpret_cast<unsigned*>(&mask[(size_t)gi * n + col0 + tx * 4])      = lo;
    *reinterpret_cast<unsigned*>(&mask[(size_t)gi * n + col0 + 64 + tx * 4]) = hi;
  }
}

// =====================================================================
// Kernel B: graph GEMM. 256x128 tile, 512 threads, 8x8/thread,
// XCD-aware decode (bz = lin % 8). w = relu(g*mask)+1e-10
// =====================================================================
__global__ __launch_bounds__(512)
void graph_kernel(const float* __restrict__ cur_, const float* __restrict__ prev,
                  const unsigned char* __restrict__ mask, float* __restrict__ wout,
                  int n, int d, int bcnt, int nbx) {
  const int lin = blockIdx.x;
  const int bz = lin % bcnt;
  const int inner = lin / bcnt;
  const int bx = inner % nbx;
  const int by = inner / nbx;
  __shared__ float Xk[GBK][260];
  __shared__ float Yk[GBK][132];
  const int t = threadIdx.x;
  const int tx = t & 15, ty = t >> 4;
  const int row0 = by * 256, col0 = bx * 128;
  const float* X = cur_ + (size_t)bz * n * d;
  const float* Y = prev + (size_t)bz * n * d;
  const int ra = t >> 1, qa = t & 1;
  const int rb = t >> 2, qb = t & 3;
  float acc[8][8] = {};
  for (int kc = 0; kc < d; kc += GBK) {
    __syncthreads();
    const float* xp = &X[(size_t)(row0 + ra) * d + kc + qa * 8];
    float4 v0 = *reinterpret_cast<const float4*>(xp);
    float4 v1 = *reinterpret_cast<const float4*>(xp + 4);
    const float* yp = &Y[(size_t)(col0 + rb) * d + kc + qb * 4];
    float4 u0 = *reinterpret_cast<const float4*>(yp);
    Xk[qa*8+0][ra] = v0.x; Xk[qa*8+1][ra] = v0.y; Xk[qa*8+2][ra] = v0.z; Xk[qa*8+3][ra] = v0.w;
    Xk[qa*8+4][ra] = v1.x; Xk[qa*8+5][ra] = v1.y; Xk[qa*8+6][ra] = v1.z; Xk[qa*8+7][ra] = v1.w;
    Yk[qb*4+0][rb] = u0.x; Yk[qb*4+1][rb] = u0.y; Yk[qb*4+2][rb] = u0.z; Yk[qb*4+3][rb] = u0.w;
    __syncthreads();
#pragma unroll
    for (int k = 0; k < GBK; ++k) {
      float4 a0 = *reinterpret_cast<const float4*>(&Xk[k][ty * 8]);
      float4 a1 = *reinterpret_cast<const float4*>(&Xk[k][ty * 8 + 4]);
      float4 b0 = *reinterpret_cast<const float4*>(&Yk[k][tx * 4]);
      float4 b1 = *reinterpret_cast<const float4*>(&Yk[k][64 + tx * 4]);
      float a[8] = {a0.x, a0.y, a0.z, a0.w, a1.x, a1.y, a1.z, a1.w};
      float b[8] = {b0.x, b0.y, b0.z, b0.w, b1.x, b1.y, b1.z, b1.w};
#pragma unroll
      for (int i2 = 0; i2 < 8; ++i2)
#pragma unroll
        for (int j2 = 0; j2 < 8; ++j2)
          acc[i2][j2] = __builtin_fmaf(a[i2], b[j2], acc[i2][j2]);
    }
  }
#pragma unroll
  for (int i2 = 0; i2 < 8; ++i2) {
    int gi = row0 + ty * 8 + i2;
    size_t rbase = (size_t)bz * n * n + (size_t)gi * n;
    unsigned mlo = *reinterpret_cast<const unsigned*>(&mask[(size_t)gi * n + col0 + tx * 4]);
    unsigned mhi = *reinterpret_cast<const unsigned*>(&mask[(size_t)gi * n + col0 + 64 + tx * 4]);
    float4 o0, o1;
    o0.x = arn(fmaxf(mrn(acc[i2][0], (float)(mlo & 0xff)), 0.0f), 1e-10f);
    o0.y = arn(fmaxf(mrn(acc[i2][1], (float)((mlo >> 8) & 0xff)), 0.0f), 1e-10f);
    o0.z = arn(fmaxf(mrn(acc[i2][2], (float)((mlo >> 16) & 0xff)), 0.0f), 1e-10f);
    o0.w = arn(fmaxf(mrn(acc[i2][3], (float)((mlo >> 24) & 0xff)), 0.0f), 1e-10f);
    o1.x = arn(fmaxf(mrn(acc[i2][4], (float)(mhi & 0xff)), 0.0f), 1e-10f);
    o1.y = arn(fmaxf(mrn(acc[i2][5], (float)((mhi >> 8) & 0xff)), 0.0f), 1e-10f);
    o1.z = arn(fmaxf(mrn(acc[i2][6], (float)((mhi >> 16) & 0xff)), 0.0f), 1e-10f);
    o1.w = arn(fmaxf(mrn(acc[i2][7], (float)((mhi >> 24) & 0xff)), 0.0f), 1e-10f);
    *reinterpret_cast<float4*>(&wout[rbase + col0 + tx * 4])      = o0;
    *reinterpret_cast<float4*>(&wout[rbase + col0 + 64 + tx * 4]) = o1;
  }
}

// =====================================================================
// Kernel C: t = sigmoid(FMA-chain dot(cur_row, pool))  [sign-critical:
// double-exp kept]
// =====================================================================
__global__ __launch_bounds__(256)
void tz_kernel(const float* __restrict__ cur, const float* __restrict__ pool,
               float* __restrict__ tv, int nrows, int d) {
  int row = blockIdx.x * 256 + threadIdx.x;
  if (row >= nrows) return;
  const float* x = cur + (size_t)row * d;
  float acc = 0.0f;
  for (int k = 0; k < d; ++k) acc = __builtin_fmaf(x[k], pool[k], acc);
  float e = (float)exp(-(double)acc);
  tv[row] = __fdiv_rn(1.0f, arn(1.0f, e));
}

// =====================================================================
// Kernel D: per-row {pairwise rowsum DAG, thr, stats partials}; row
// LDS-staged once. __expf on the stats value-path only.
// =====================================================================
__global__ __launch_bounds__(256)
void rowstat_kernel(const float* __restrict__ wbuf, const float* __restrict__ tv,
                    float* __restrict__ rsv, float* __restrict__ thrv,
                    double* __restrict__ cpart, int n) {
  const int row = blockIdx.x;
  const int t = threadIdx.x;
  const float* a = wbuf + (size_t)row * n;
  const int i = row % n;
  __shared__ float sr[2048];
  *reinterpret_cast<float4*>(&sr[t * 4])        = *reinterpret_cast<const float4*>(&a[t * 4]);
  *reinterpret_cast<float4*>(&sr[1024 + t * 4]) = *reinterpret_cast<const float4*>(&a[1024 + t * 4]);
  __syncthreads();
  const int kleaf = t >> 4, l = t & 15;
  __shared__ float leaf[16];
  __shared__ float sh_rs, sh_thr;
  {
    const float* base = sr + kleaf * 128;
    float r0 = base[l],      r1 = base[16 + l],  r2 = base[32 + l],  r3 = base[48 + l];
    float r4 = base[64 + l], r5 = base[80 + l],  r6 = base[96 + l],  r7 = base[112 + l];
    float v = arn(arn(arn(r0, r1), arn(r2, r3)), arn(arn(r4, r5), arn(r6, r7)));
    v = arn(v, __shfl_xor(v, 8));
    v = arn(v, __shfl_xor(v, 4));
    v = arn(v, __shfl_xor(v, 2));
    v = arn(v, __shfl_xor(v, 1));
    if (l == 0) leaf[kleaf] = v;
  }
  __syncthreads();
  if (t == 0) {
    float t1[8], t2[4], t3[2];
#pragma unroll
    for (int k2 = 0; k2 < 8; ++k2) t1[k2] = arn(leaf[2*k2], leaf[2*k2+1]);
#pragma unroll
    for (int k2 = 0; k2 < 4; ++k2) t2[k2] = arn(t1[2*k2], t1[2*k2+1]);
#pragma unroll
    for (int k2 = 0; k2 < 2; ++k2) t3[k2] = arn(t2[2*k2], t2[2*k2+1]);
    float rs = arn(t3[0], t3[1]);
    float tb = __fdiv_rn(sr[i], rs);
    float th = mrn(tb, tv[row]);
    sh_rs = rs; sh_thr = th;
    rsv[row] = rs; thrv[row] = th;
  }
  __syncthreads();
  const float rs = sh_rs, thr = sh_thr;
  double s1 = 0.0, s2 = 0.0;
  for (int off = 0; off < n; off += 1024) {
    float4 wv = *reinterpret_cast<const float4*>(&sr[off + t * 4]);
    float wa[4] = {wv.x, wv.y, wv.z, wv.w};
#pragma unroll
    for (int c = 0; c < 4; ++c) {
      float probs = __fdiv_rn(wa[c], rs);
      float x = __fsub_rn(probs, thr);
      if (x >= 0.0f) {
        float pv = __fdiv_rn(1.0f, arn(1.0f, __expf(-x)));
        s1 += (double)pv;
        s2 += (double)pv * (double)pv;
      }
    }
  }
  __shared__ double sh1[256], sh2[256];
  sh1[t] = s1; sh2[t] = s2;
  __syncthreads();
  for (int s = 128; s > 0; s >>= 1) {
    if (t < s) { sh1[t] += sh1[t + s]; sh2[t] += sh2[t + s]; }
    __syncthreads();
  }
  if (t == 0) {
    cpart[(size_t)row * 2 + 0] = sh1[0];
    cpart[(size_t)row * 2 + 1] = sh2[0];
  }
}

// =====================================================================
// Kernel E: per-batch mean / inv-std (biased) from per-row partials
// =====================================================================
__global__ __launch_bounds__(256)
void stats_kernel(const double* __restrict__ cpart, float* __restrict__ bstats,
                  int nb, double inv_nn) {
  int b = blockIdx.x, t = threadIdx.x;
  double s1 = 0.0, s2 = 0.0;
  for (int c = t; c < nb; c += 256) {
    s1 += cpart[((size_t)b * nb + c) * 2 + 0];
    s2 += cpart[((size_t)b * nb + c) * 2 + 1];
  }
  __shared__ double sh1[256], sh2[256];
  sh1[t] = s1; sh2[t] = s2;
  __syncthreads();
  for (int s = 128; s > 0; s >>= 1) {
    if (t < s) { sh1[t] += sh1[t + s]; sh2[t] += sh2[t + s]; }
    __syncthreads();
  }
  if (t == 0) {
    double mean = sh1[0] * inv_nn;
    double var = sh2[0] * inv_nn - mean * mean;
    bstats[b * 2 + 0] = (float)mean;
    bstats[b * 2 + 1] = (float)(1.0 / sqrt(var + 1e-5));
  }
}

// =====================================================================
// Kernel F: phi in-place. 2D grid (row = blockIdx.y) — no integer
// division per thread. Sign chain identical (__fdiv_rn/__fsub_rn);
// __expf on value-paths.
// =====================================================================
__global__ __launch_bounds__(256)
void phi_kernel(float4* __restrict__ buf, const float* __restrict__ rsv,
                const float* __restrict__ thrv, const float* __restrict__ bstats,
                const float* __restrict__ gamma, const float* __restrict__ beta,
                int nq4, int n) {
  const int row = blockIdx.y;
  const int b = row / n;                 // scalar, once per block
  size_t idx = (size_t)row * nq4 + blockIdx.x * 256 + threadIdx.x;
  float rs = rsv[row], thr = thrv[row];
  float mean = bstats[b * 2 + 0];
  float inv = bstats[b * 2 + 1];
  float ga = gamma[0] * 2.0f;
  float be = beta[0] * 2.0f;
  float4 v = buf[idx];
  float wa[4] = {v.x, v.y, v.z, v.w};
  float oa[4];
#pragma unroll
  for (int c = 0; c < 4; ++c) {
    float probs = __fdiv_rn(wa[c], rs);
    float x = __fsub_rn(probs, thr);
    float p = 0.0f, m = 1.0f;
    if (x >= 0.0f) {
      p = __fdiv_rn(1.0f, arn(1.0f, __expf(-x)));
      m = p;
    }
    float xn = (p - mean) * inv;
    oa[c] = __expf(__builtin_fmaf(ga, xn, be)) * m;
  }
  v.x = oa[0]; v.y = oa[1]; v.z = oa[2]; v.w = oa[3];
  buf[idx] = v;
}

extern "C" void kernel_launch(void* const* d_in, const int* in_sizes, int n_in,
                              void* d_out, int out_size, void* d_ws, size_t ws_size,
                              hipStream_t stream) {
  const float* S     = (const float*)d_in[0];
  const float* cur   = (const float*)d_in[1];
  const float* prev  = (const float*)d_in[2];
  const float* pool  = (const float*)d_in[3];
  const float* gamma = (const float*)d_in[4];
  const float* beta  = (const float*)d_in[5];
  const int d = in_sizes[3];
  const int n = in_sizes[0] / d;
  const int b = in_sizes[1] / (n * d);
  float* out = (float*)d_out;

  const int nrows = b * n;
  const int nbx = n / 128, nby = n / 256;

  char* ws = (char*)d_ws;
  float* tv   = (float*)ws; ws += (size_t)nrows * sizeof(float);
  float* rsv  = (float*)ws; ws += (size_t)nrows * sizeof(float);
  float* thrv = (float*)ws; ws += (size_t)nrows * sizeof(float);
  ws = (char*)(((uintptr_t)ws + 15) & ~(uintptr_t)15);
  double* cpart = (double*)ws; ws += (size_t)nrows * 2 * sizeof(double);
  float* bstats = (float*)ws;  ws += 64;
  unsigned char* mask = (unsigned char*)ws;   // n*n bytes

  hipLaunchKernelGGL(mask_kernel, dim3(n / 128, n / 128), dim3(256), 0, stream,
                     S, mask, n, d);
  hipLaunchKernelGGL(tz_kernel, dim3((nrows + 255) / 256), dim3(256), 0, stream,
                     cur, pool, tv, nrows, d);
  hipLaunchKernelGGL(graph_kernel, dim3(nbx * nby * b), dim3(512), 0, stream,
                     cur, prev, mask, out, n, d, b, nbx);
  hipLaunchKernelGGL(rowstat_kernel, dim3(nrows), dim3(256), 0, stream,
                     out, tv, rsv, thrv, cpart, n);
  hipLaunchKernelGGL(stats_kernel, dim3(b), dim3(256), 0, stream,
                     cpart, bstats, n, 1.0 / ((double)n * (double)n));
  hipLaunchKernelGGL(phi_kernel, dim3(n / 1024, nrows), dim3(256), 0, stream,
                     (float4*)out, rsv, thrv, bstats, gamma, beta, n / 4, n);
}